// Round 7
// baseline (532.972 us; speedup 1.0000x reference)
//
#include <hip/hip_runtime.h>
#include <math.h>

#define N_NODES 20000
#define E_ORIG  320000
#define E_TOT   340000
#define NUM_GRAPHS 64
#define NCHUNK 5            // src chunks of 4096 rows -> (dst,chunk) binned CSR
#define NBINS (N_NODES * NCHUNK)

typedef __attribute__((ext_vector_type(8))) short bf16x8;
typedef __attribute__((ext_vector_type(4))) float f32x4;

// fp32 -> bf16 RNE
__device__ __forceinline__ ushort f2bf(float x) {
  unsigned u = __float_as_uint(x);
  return (ushort)((u + 0x7fffu + ((u >> 16) & 1u)) >> 16);
}
// 4 consecutive bf16 -> float4 (8B load)
__device__ __forceinline__ float4 ld_bf16x4(const ushort* p) {
  ushort4 u = *(const ushort4*)p;
  float4 f;
  f.x = __uint_as_float((unsigned)u.x << 16);
  f.y = __uint_as_float((unsigned)u.y << 16);
  f.z = __uint_as_float((unsigned)u.z << 16);
  f.w = __uint_as_float((unsigned)u.w << 16);
  return f;
}
// async global->LDS, 16B per lane; lds dest is wave-uniform base + lane*16
__device__ __forceinline__ void gl_lds16(const void* g, void* l) {
  __builtin_amdgcn_global_load_lds(
      (const __attribute__((address_space(1))) unsigned*)(uintptr_t)g,
      (__attribute__((address_space(3))) unsigned*)(uintptr_t)l, 16, 0, 0);
}

// ============ merged prep: cast x, pack weights, zero (dst,chunk) bins ======
__global__ __launch_bounds__(256) void prep(
    const float* __restrict__ x,
    const float* __restrict__ Wl0, const float* __restrict__ Wr0,
    const float* __restrict__ Wl1, const float* __restrict__ Wr1,
    const float* __restrict__ Wl2, const float* __restrict__ Wr2,
    ushort* __restrict__ x16, ushort* __restrict__ Bt0,
    ushort* __restrict__ Bt1, ushort* __restrict__ Bt2, int* __restrict__ deg)
{
  const int Z0 = 640000;           // x cast, float4 granules (20000*128/4)
  const int Z1 = Z0 + 65536;       // Bt0: 512(n) x 128(k)
  const int Z2 = Z1 + 131072;      // Bt1: 512 x 256
  const int Z3 = Z2 + 32768;       // Bt2: 128 x 256
  const int Z4 = Z3 + NBINS / 4;   // deg zero, int4 granules (100000 ints)
  int t = blockIdx.x * 256 + threadIdx.x;
  if (t < Z0) {
    int i = t << 2;
    float4 v = *(const float4*)&x[i];
    ushort4 o; o.x = f2bf(v.x); o.y = f2bf(v.y); o.z = f2bf(v.z); o.w = f2bf(v.w);
    *(ushort4*)&x16[i] = o;
  } else if (t < Z1) {
    int idx = t - Z0; int n = idx >> 7, k = idx & 127;
    float v = (n < 256) ? Wl0[k * 256 + n] : Wr0[k * 256 + (n - 256)];
    Bt0[idx] = f2bf(v);
  } else if (t < Z2) {
    int idx = t - Z1; int n = idx >> 8, k = idx & 255;
    float v = (n < 256) ? Wl1[k * 256 + n] : Wr1[k * 256 + (n - 256)];
    Bt1[idx] = f2bf(v);
  } else if (t < Z3) {
    int idx = t - Z2; int n = idx >> 8, k = idx & 255;
    float v = (n < 64) ? Wl2[k * 64 + n] : Wr2[k * 64 + (n - 64)];
    Bt2[idx] = f2bf(v);
  } else if (t < Z4) {
    int4 z = {0, 0, 0, 0};
    *(int4*)&deg[(t - Z3) << 2] = z;
  }
}

// ============ CSR build, binned by (dst, src-chunk) ============
// Lists come out chunk-sorted per dst -> concurrent waves hit the same
// 2MB Cbig window -> per-XCD L2 reuse (softmax is order-independent).

__global__ __launch_bounds__(256) void deg_count(
    const int* __restrict__ esrc, const int* __restrict__ edst,
    int* __restrict__ deg)
{
  int e = blockIdx.x * 256 + threadIdx.x;
  if (e >= E_TOT) return;
  int src, dst;
  if (e < E_ORIG) { src = esrc[e]; dst = edst[e]; }
  else            { src = dst = e - E_ORIG; }
  atomicAdd(&deg[dst * NCHUNK + (src >> 12)], 1);
}

__global__ __launch_bounds__(1024) void scan_rowptr(
    const int* __restrict__ deg, int* __restrict__ rowptr, int* __restrict__ cursor)
{
  __shared__ int part[1024];
  const int t = threadIdx.x;
  const int CH = (NBINS + 1023) / 1024;    // 98
  int base = t * CH;
  int s = 0;
  for (int i = 0; i < CH; i++) {
    int idx = base + i;
    if (idx < NBINS) s += deg[idx];
  }
  part[t] = s;
  __syncthreads();
  for (int off = 1; off < 1024; off <<= 1) {
    int v = (t >= off) ? part[t - off] : 0;
    __syncthreads();
    part[t] += v;
    __syncthreads();
  }
  int run = (t == 0) ? 0 : part[t - 1];
  for (int i = 0; i < CH; i++) {
    int idx = base + i;
    if (idx < NBINS) {
      rowptr[idx] = run;
      cursor[idx] = run;
      run += deg[idx];
    }
  }
  if (t == 1023) rowptr[NBINS] = part[1023];
}

__global__ __launch_bounds__(256) void csr_fill(
    const int* __restrict__ esrc, const int* __restrict__ edst,
    int* __restrict__ cursor, int* __restrict__ csr_src)
{
  int e = blockIdx.x * 256 + threadIdx.x;
  if (e >= E_TOT) return;
  int src, dst;
  if (e < E_ORIG) { src = esrc[e]; dst = edst[e]; }
  else            { src = dst = e - E_ORIG; }
  int pos = atomicAdd(&cursor[dst * NCHUNK + (src >> 12)], 1);
  csr_src[pos] = src;
}

// ============ bf16 MFMA GEMM: C[M,N] = A[M,K] @ Bt[N,K]^T ============
// BK=64, 128x128 tile, XCD-swizzled, LDS-repacked coalesced epilogue.
__global__ __launch_bounds__(256) void mfma_gemm_bf16(
    const ushort* __restrict__ A, const ushort* __restrict__ Bt,
    ushort* __restrict__ C, int M, int K, int N)
{
  __shared__ char smem[36864];
  ushort* As = (ushort*)smem;           // [128][64]
  ushort* Bs = As + 8192;               // [128][64]

  const int mtiles = (M + 127) >> 7;
  const int bid = blockIdx.x;
  const int xcd = bid & 7;
  const int i = bid >> 3;
  const int n0 = (i / 20) << 7;
  const int m = xcd + ((i % 20) << 3);
  if (m >= mtiles) return;
  const int m0 = m << 7;

  const int tid = threadIdx.x;
  const int lane = tid & 63;
  const int w = tid >> 6;
  const int wm = (w >> 1) << 6;
  const int wn = (w & 1) << 6;
  const int quad = lane >> 4;
  const int l15 = lane & 15;

  f32x4 acc[4][4] = {};

  for (int k0 = 0; k0 < K; k0 += 64) {
    #pragma unroll
    for (int r = 0; r < 4; r++) {
      int c = (r << 8) + tid;
      int row = c >> 3;
      int col = (c & 7) << 3;
      int ga = m0 + row; if (ga >= M) ga = M - 1;
      gl_lds16(A  + (size_t)ga * K + k0 + col, (char*)As + c * 16);
      gl_lds16(Bt + (size_t)(n0 + row) * K + k0 + col, (char*)Bs + c * 16);
    }
    __syncthreads();
    #pragma unroll
    for (int ks = 0; ks < 2; ks++) {
      bf16x8 af[4], bfr[4];
      #pragma unroll
      for (int ii = 0; ii < 4; ii++)
        af[ii]  = *(const bf16x8*)&As[(wm + (ii << 4) + l15) * 64 + (ks << 5) + (quad << 3)];
      #pragma unroll
      for (int j = 0; j < 4; j++)
        bfr[j] = *(const bf16x8*)&Bs[(wn + (j << 4) + l15) * 64 + (ks << 5) + (quad << 3)];
      #pragma unroll
      for (int ii = 0; ii < 4; ii++)
        #pragma unroll
        for (int j = 0; j < 4; j++)
          acc[ii][j] = __builtin_amdgcn_mfma_f32_16x16x32_bf16(
              af[ii], bfr[j], acc[ii][j], 0, 0, 0);
    }
    __syncthreads();
  }

  ushort* Cs = (ushort*)smem + w * 4608;
  #pragma unroll
  for (int ii = 0; ii < 4; ii++)
    #pragma unroll
    for (int j = 0; j < 4; j++)
      #pragma unroll
      for (int r = 0; r < 4; r++)
        Cs[((ii << 4) + (quad << 2) + r) * 72 + (j << 4) + l15] = f2bf(acc[ii][j][r]);
  #pragma unroll
  for (int it = 0; it < 8; it++) {
    int row = (it << 3) + (lane >> 3);
    int cc = lane & 7;
    bf16x8 v = *(const bf16x8*)&Cs[row * 72 + (cc << 3)];
    int grow = m0 + wm + row;
    if (grow < M)
      *(bf16x8*)&C[(size_t)grow * N + n0 + wn + (cc << 3)] = v;
  }
}

// ============ GATv2 edge phase, H=4, bf16, 4-wide unrolled ============
__device__ __forceinline__ void h4_term(
    float4 xlv, const float4& xrv, const float4& attv, float& v)
{
  float4 a;
  a.x = xlv.x + xrv.x; a.y = xlv.y + xrv.y;
  a.z = xlv.z + xrv.z; a.w = xlv.w + xrv.w;
  a.x = fmaxf(a.x, 0.2f * a.x); a.y = fmaxf(a.y, 0.2f * a.y);
  a.z = fmaxf(a.z, 0.2f * a.z); a.w = fmaxf(a.w, 0.2f * a.w);
  v = a.x * attv.x + a.y * attv.y + a.z * attv.z + a.w * attv.w;
}

__global__ __launch_bounds__(256) void gat_gather_h4(
    const ushort* __restrict__ Cin, const float* __restrict__ att,
    const float* __restrict__ bias, const int* __restrict__ rowptr,
    const int* __restrict__ csr_src, ushort* __restrict__ hout)
{
  const int n = blockIdx.x * 4 + (threadIdx.x >> 6);
  const int lane = threadIdx.x & 63;
  const int c4 = lane << 2;
  const float4 xrv  = ld_bf16x4(Cin + (size_t)n * 512 + 256 + c4);
  const float4 attv = *(const float4*)&att[c4];
  const int beg = rowptr[n * NCHUNK], end = rowptr[n * NCHUNK + NCHUNK];
  float4 acc = make_float4(0.f, 0.f, 0.f, 0.f);
  float lsum = 0.f;
  int p = beg;
  for (; p + 3 < end; p += 4) {
    int s0 = csr_src[p],     s1 = csr_src[p + 1];
    int s2 = csr_src[p + 2], s3 = csr_src[p + 3];
    float4 x0 = ld_bf16x4(Cin + (size_t)s0 * 512 + c4);
    float4 x1 = ld_bf16x4(Cin + (size_t)s1 * 512 + c4);
    float4 x2 = ld_bf16x4(Cin + (size_t)s2 * 512 + c4);
    float4 x3 = ld_bf16x4(Cin + (size_t)s3 * 512 + c4);
    float v0, v1, v2, v3;
    h4_term(x0, xrv, attv, v0); h4_term(x1, xrv, attv, v1);
    h4_term(x2, xrv, attv, v2); h4_term(x3, xrv, attv, v3);
    v0 += __shfl_xor(v0, 1); v1 += __shfl_xor(v1, 1);
    v2 += __shfl_xor(v2, 1); v3 += __shfl_xor(v3, 1);
    v0 += __shfl_xor(v0, 2); v1 += __shfl_xor(v1, 2);
    v2 += __shfl_xor(v2, 2); v3 += __shfl_xor(v3, 2);
    v0 += __shfl_xor(v0, 4); v1 += __shfl_xor(v1, 4);
    v2 += __shfl_xor(v2, 4); v3 += __shfl_xor(v3, 4);
    v0 += __shfl_xor(v0, 8); v1 += __shfl_xor(v1, 8);
    v2 += __shfl_xor(v2, 8); v3 += __shfl_xor(v3, 8);
    float w0 = __expf(v0), w1 = __expf(v1);
    float w2 = __expf(v2), w3 = __expf(v3);
    lsum += (w0 + w1) + (w2 + w3);
    acc.x += w0 * x0.x + w1 * x1.x + w2 * x2.x + w3 * x3.x;
    acc.y += w0 * x0.y + w1 * x1.y + w2 * x2.y + w3 * x3.y;
    acc.z += w0 * x0.z + w1 * x1.z + w2 * x2.z + w3 * x3.z;
    acc.w += w0 * x0.w + w1 * x1.w + w2 * x2.w + w3 * x3.w;
  }
  for (; p < end; p++) {
    int s0 = csr_src[p];
    float4 x0 = ld_bf16x4(Cin + (size_t)s0 * 512 + c4);
    float v0;
    h4_term(x0, xrv, attv, v0);
    v0 += __shfl_xor(v0, 1);
    v0 += __shfl_xor(v0, 2);
    v0 += __shfl_xor(v0, 4);
    v0 += __shfl_xor(v0, 8);
    float w0 = __expf(v0);
    lsum += w0;
    acc.x += w0 * x0.x; acc.y += w0 * x0.y; acc.z += w0 * x0.z; acc.w += w0 * x0.w;
  }
  const float4 bv = *(const float4*)&bias[c4];
  float inv = 1.f / lsum;
  ushort4 o;
  o.x = f2bf(acc.x * inv + bv.x); o.y = f2bf(acc.y * inv + bv.y);
  o.z = f2bf(acc.z * inv + bv.z); o.w = f2bf(acc.w * inv + bv.w);
  *(ushort4*)&hout[(size_t)n * 256 + c4] = o;
}

// ============ layer 2 (H=1): 4 edges/wave via 16-lane groups ============
__global__ __launch_bounds__(256) void gat_gather_h1(
    const ushort* __restrict__ Cin, const float* __restrict__ att,
    const float* __restrict__ bias, const int* __restrict__ rowptr,
    const int* __restrict__ csr_src, float* __restrict__ h3)
{
  const int n = blockIdx.x * 4 + (threadIdx.x >> 6);
  const int lane = threadIdx.x & 63;
  const int g = lane >> 4, c4 = (lane & 15) << 2;
  const float4 xrv  = ld_bf16x4(Cin + (size_t)n * 128 + 64 + c4);
  const float4 attv = *(const float4*)&att[c4];
  const int beg = rowptr[n * NCHUNK], end = rowptr[n * NCHUNK + NCHUNK];
  float4 acc = make_float4(0.f, 0.f, 0.f, 0.f);
  float lsum = 0.f;
  for (int p = beg + g; p < end; p += 4) {
    int src = csr_src[p];
    float4 xlv = ld_bf16x4(Cin + (size_t)src * 128 + c4);
    float v;
    h4_term(xlv, xrv, attv, v);
    v += __shfl_xor(v, 1);
    v += __shfl_xor(v, 2);
    v += __shfl_xor(v, 4);
    v += __shfl_xor(v, 8);
    float w = __expf(v);
    lsum += w;
    acc.x += w * xlv.x; acc.y += w * xlv.y;
    acc.z += w * xlv.z; acc.w += w * xlv.w;
  }
  #pragma unroll
  for (int off = 16; off <= 32; off <<= 1) {
    lsum  += __shfl_xor(lsum, off);
    acc.x += __shfl_xor(acc.x, off); acc.y += __shfl_xor(acc.y, off);
    acc.z += __shfl_xor(acc.z, off); acc.w += __shfl_xor(acc.w, off);
  }
  if (g == 0) {
    const float4 bv = *(const float4*)&bias[c4];
    float inv = 1.f / lsum;
    float4 o;
    o.x = acc.x * inv + bv.x; o.y = acc.y * inv + bv.y;
    o.z = acc.z * inv + bv.z; o.w = acc.w * inv + bv.w;
    *(float4*)&h3[(size_t)n * 64 + c4] = o;
  }
}

// ============ fused segmented pool (batch sorted) + BN + fc ============
__global__ __launch_bounds__(256) void pool_bn_fc(
    const float* __restrict__ h3, const int* __restrict__ batch,
    const float* __restrict__ gamma, const float* __restrict__ beta,
    const float* __restrict__ mean, const float* __restrict__ var,
    const float* __restrict__ fcw, const float* __restrict__ fcb,
    float* __restrict__ out)
{
  __shared__ float red[256];
  __shared__ float s[64];
  const int g = blockIdx.x;
  const int t = threadIdx.x;
  const int c = t & 63, r = t >> 6;
  int lo = 0, hi = N_NODES;
  while (lo < hi) { int mid = (lo + hi) >> 1; if (batch[mid] < g) lo = mid + 1; else hi = mid; }
  int s0 = lo;
  hi = N_NODES;
  while (lo < hi) { int mid = (lo + hi) >> 1; if (batch[mid] < g + 1) lo = mid + 1; else hi = mid; }
  int e0 = lo;
  float a = 0.f;
  for (int n = s0 + r; n < e0; n += 4) a += h3[(size_t)n * 64 + c];
  red[t] = a;
  __syncthreads();
  if (r == 0) {
    float p = red[c] + red[c + 64] + red[c + 128] + red[c + 192];
    s[c] = (p - mean[c]) * rsqrtf(var[c] + 1e-5f) * gamma[c] + beta[c];
  }
  __syncthreads();
  if (t < 32) {
    float acc = fcb[t];
    #pragma unroll
    for (int k = 0; k < 64; k++) acc += s[k] * fcw[k * 32 + t];
    out[g * 32 + t] = acc;
  }
}

extern "C" void kernel_launch(void* const* d_in, const int* in_sizes, int n_in,
                              void* d_out, int out_size, void* d_ws, size_t ws_size,
                              hipStream_t stream) {
  const float* x    = (const float*)d_in[0];
  const int*   ei   = (const int*)d_in[1];
  const int*   batch= (const int*)d_in[2];
  const float* Wl0  = (const float*)d_in[3];
  const float* Wr0  = (const float*)d_in[4];
  const float* att0 = (const float*)d_in[5];
  const float* b0   = (const float*)d_in[6];
  const float* Wl1  = (const float*)d_in[7];
  const float* Wr1  = (const float*)d_in[8];
  const float* att1 = (const float*)d_in[9];
  const float* b1   = (const float*)d_in[10];
  const float* Wl2  = (const float*)d_in[11];
  const float* Wr2  = (const float*)d_in[12];
  const float* att2 = (const float*)d_in[13];
  const float* b2   = (const float*)d_in[14];
  const float* bng  = (const float*)d_in[15];
  const float* bnb  = (const float*)d_in[16];
  const float* bnm  = (const float*)d_in[17];
  const float* bnv  = (const float*)d_in[18];
  const float* fcw  = (const float*)d_in[19];
  const float* fcb  = (const float*)d_in[20];
  float* out = (float*)d_out;

  const int* esrc = ei;
  const int* edst = ei + E_ORIG;

  // ---- workspace layout ----
  char* w = (char*)d_ws;
  ushort* x16  = (ushort*)w;                 w += (size_t)N_NODES * 128 * 2;
  ushort* Cbig = (ushort*)w;                 w += (size_t)N_NODES * 512 * 2;
  ushort* h16  = (ushort*)w;                 w += (size_t)N_NODES * 256 * 2;
  ushort* C2   = (ushort*)w;                 w += (size_t)N_NODES * 128 * 2;
  float*  h3   = (float*)w;                  w += (size_t)N_NODES * 64 * 4;
  ushort* Bt0  = (ushort*)w;                 w += (size_t)512 * 128 * 2;
  ushort* Bt1  = (ushort*)w;                 w += (size_t)512 * 256 * 2;
  ushort* Bt2  = (ushort*)w;                 w += (size_t)128 * 256 * 2;
  int* deg     = (int*)w;                    w += NBINS * 4;
  int* rowptr  = (int*)w;                    w += (NBINS + 1) * 4;
  int* cursor  = (int*)w;                    w += NBINS * 4;
  int* csr_src = (int*)w;

  dim3 blk(256);
  const int eblk = (E_TOT + 255) / 256;

  // ---- prep: cast + pack all weights + zero bins (one launch) ----
  prep<<<dim3(3495), blk, 0, stream>>>(
      x, Wl0, Wr0, Wl1, Wr1, Wl2, Wr2, x16, Bt0, Bt1, Bt2, deg);

  // ---- CSR build, (dst, src-chunk) binned ----
  deg_count<<<dim3(eblk), blk, 0, stream>>>(esrc, edst, deg);
  scan_rowptr<<<dim3(1), dim3(1024), 0, stream>>>(deg, rowptr, cursor);
  csr_fill<<<dim3(eblk), blk, 0, stream>>>(esrc, edst, cursor, csr_src);

  // ---- layer 0 ----
  mfma_gemm_bf16<<<dim3(160 * 4), blk, 0, stream>>>(x16, Bt0, Cbig, N_NODES, 128, 512);
  gat_gather_h4<<<dim3(N_NODES / 4), blk, 0, stream>>>(
      Cbig, att0, b0, rowptr, csr_src, h16);

  // ---- layer 1 ----
  mfma_gemm_bf16<<<dim3(160 * 4), blk, 0, stream>>>(h16, Bt1, Cbig, N_NODES, 256, 512);
  gat_gather_h4<<<dim3(N_NODES / 4), blk, 0, stream>>>(
      Cbig, att1, b1, rowptr, csr_src, h16);

  // ---- layer 2 ----
  mfma_gemm_bf16<<<dim3(160 * 1), blk, 0, stream>>>(h16, Bt2, C2, N_NODES, 256, 128);
  gat_gather_h1<<<dim3(N_NODES / 4), blk, 0, stream>>>(
      C2, att2, b2, rowptr, csr_src, h3);

  // ---- pool + BN + fc ----
  pool_bn_fc<<<dim3(NUM_GRAPHS), blk, 0, stream>>>(
      h3, batch, bng, bnb, bnm, bnv, fcw, fcb, out);
}

// Round 8
// 289.628 us; speedup vs baseline: 1.8402x; 1.8402x over previous
//
#include <hip/hip_runtime.h>
#include <math.h>

#define N_NODES 20000
#define E_ORIG  320000
#define E_TOT   340000
#define NUM_GRAPHS 64
#define NCHUNK 5            // src chunks of 4096 rows -> (dst,chunk) binned CSR
#define NBINS (N_NODES * NCHUNK)
#define SCAN_BLOCKS 98      // 98 * 1024 = 100352 >= NBINS

typedef __attribute__((ext_vector_type(8))) short bf16x8;
typedef __attribute__((ext_vector_type(4))) float f32x4;

// fp32 -> bf16 RNE
__device__ __forceinline__ ushort f2bf(float x) {
  unsigned u = __float_as_uint(x);
  return (ushort)((u + 0x7fffu + ((u >> 16) & 1u)) >> 16);
}
// 4 consecutive bf16 -> float4 (8B load)
__device__ __forceinline__ float4 ld_bf16x4(const ushort* p) {
  ushort4 u = *(const ushort4*)p;
  float4 f;
  f.x = __uint_as_float((unsigned)u.x << 16);
  f.y = __uint_as_float((unsigned)u.y << 16);
  f.z = __uint_as_float((unsigned)u.z << 16);
  f.w = __uint_as_float((unsigned)u.w << 16);
  return f;
}
// async global->LDS, 16B per lane; lds dest is wave-uniform base + lane*16
__device__ __forceinline__ void gl_lds16(const void* g, void* l) {
  __builtin_amdgcn_global_load_lds(
      (const __attribute__((address_space(1))) unsigned*)(uintptr_t)g,
      (__attribute__((address_space(3))) unsigned*)(uintptr_t)l, 16, 0, 0);
}

// ============ merged prep: cast x, pack weights, zero (dst,chunk) bins ======
__global__ __launch_bounds__(256) void prep(
    const float* __restrict__ x,
    const float* __restrict__ Wl0, const float* __restrict__ Wr0,
    const float* __restrict__ Wl1, const float* __restrict__ Wr1,
    const float* __restrict__ Wl2, const float* __restrict__ Wr2,
    ushort* __restrict__ x16, ushort* __restrict__ Bt0,
    ushort* __restrict__ Bt1, ushort* __restrict__ Bt2, int* __restrict__ deg)
{
  const int Z0 = 640000;           // x cast, float4 granules (20000*128/4)
  const int Z1 = Z0 + 65536;       // Bt0: 512(n) x 128(k)
  const int Z2 = Z1 + 131072;      // Bt1: 512 x 256
  const int Z3 = Z2 + 32768;       // Bt2: 128 x 256
  const int Z4 = Z3 + NBINS / 4;   // deg zero, int4 granules (100000 ints)
  int t = blockIdx.x * 256 + threadIdx.x;
  if (t < Z0) {
    int i = t << 2;
    float4 v = *(const float4*)&x[i];
    ushort4 o; o.x = f2bf(v.x); o.y = f2bf(v.y); o.z = f2bf(v.z); o.w = f2bf(v.w);
    *(ushort4*)&x16[i] = o;
  } else if (t < Z1) {
    int idx = t - Z0; int n = idx >> 7, k = idx & 127;
    float v = (n < 256) ? Wl0[k * 256 + n] : Wr0[k * 256 + (n - 256)];
    Bt0[idx] = f2bf(v);
  } else if (t < Z2) {
    int idx = t - Z1; int n = idx >> 8, k = idx & 255;
    float v = (n < 256) ? Wl1[k * 256 + n] : Wr1[k * 256 + (n - 256)];
    Bt1[idx] = f2bf(v);
  } else if (t < Z3) {
    int idx = t - Z2; int n = idx >> 8, k = idx & 255;
    float v = (n < 64) ? Wl2[k * 64 + n] : Wr2[k * 64 + (n - 64)];
    Bt2[idx] = f2bf(v);
  } else if (t < Z4) {
    int4 z = {0, 0, 0, 0};
    *(int4*)&deg[(t - Z3) << 2] = z;
  }
}

// ============ CSR build, binned by (dst, src-chunk) ============

__global__ __launch_bounds__(256) void deg_count(
    const int* __restrict__ esrc, const int* __restrict__ edst,
    int* __restrict__ deg)
{
  int e = blockIdx.x * 256 + threadIdx.x;
  if (e >= E_TOT) return;
  int src, dst;
  if (e < E_ORIG) { src = esrc[e]; dst = edst[e]; }
  else            { src = dst = e - E_ORIG; }
  atomicAdd(&deg[dst * NCHUNK + (src >> 12)], 1);
}

// ---- 3-phase parallel exclusive scan over deg[NBINS] ----
// phase 1: per-block (1024 ints) reduction -> bsum[SCAN_BLOCKS]
__global__ __launch_bounds__(256) void scan1(
    const int* __restrict__ deg, int* __restrict__ bsum)
{
  __shared__ int red[256];
  const int t = threadIdx.x;
  int base = (blockIdx.x << 10) + (t << 2);
  int s = 0;
  if (base + 4 <= NBINS) {
    int4 v = *(const int4*)&deg[base];
    s = v.x + v.y + v.z + v.w;
  }
  red[t] = s;
  __syncthreads();
  #pragma unroll
  for (int off = 128; off > 0; off >>= 1) {
    if (t < off) red[t] += red[t + off];
    __syncthreads();
  }
  if (t == 0) bsum[blockIdx.x] = red[0];
}

// phase 2: scan SCAN_BLOCKS partials (tiny, 1 block) -> boff, rowptr[NBINS]
__global__ __launch_bounds__(128) void scan2(
    const int* __restrict__ bsum, int* __restrict__ boff,
    int* __restrict__ rowptr)
{
  __shared__ int s[128];
  const int t = threadIdx.x;
  s[t] = (t < SCAN_BLOCKS) ? bsum[t] : 0;
  __syncthreads();
  #pragma unroll
  for (int off = 1; off < 128; off <<= 1) {
    int v = (t >= off) ? s[t - off] : 0;
    __syncthreads();
    s[t] += v;
    __syncthreads();
  }
  if (t < SCAN_BLOCKS) boff[t] = (t == 0) ? 0 : s[t - 1];
  if (t == 127) rowptr[NBINS] = s[127];
}

// phase 3: per-block local scan + offset -> rowptr, cursor
__global__ __launch_bounds__(256) void scan3(
    const int* __restrict__ deg, const int* __restrict__ boff,
    int* __restrict__ rowptr, int* __restrict__ cursor)
{
  __shared__ int sc[256];
  const int t = threadIdx.x;
  int base = (blockIdx.x << 10) + (t << 2);
  int4 v = {0, 0, 0, 0};
  if (base + 4 <= NBINS) v = *(const int4*)&deg[base];
  int s = v.x + v.y + v.z + v.w;
  sc[t] = s;
  __syncthreads();
  #pragma unroll
  for (int off = 1; off < 256; off <<= 1) {
    int u = (t >= off) ? sc[t - off] : 0;
    __syncthreads();
    sc[t] += u;
    __syncthreads();
  }
  if (base + 4 <= NBINS) {
    int p = boff[blockIdx.x] + ((t == 0) ? 0 : sc[t - 1]);
    int4 r;
    r.x = p; r.y = p + v.x; r.z = r.y + v.y; r.w = r.z + v.z;
    *(int4*)&rowptr[base] = r;
    *(int4*)&cursor[base] = r;
  }
}

__global__ __launch_bounds__(256) void csr_fill(
    const int* __restrict__ esrc, const int* __restrict__ edst,
    int* __restrict__ cursor, int* __restrict__ csr_src)
{
  int e = blockIdx.x * 256 + threadIdx.x;
  if (e >= E_TOT) return;
  int src, dst;
  if (e < E_ORIG) { src = esrc[e]; dst = edst[e]; }
  else            { src = dst = e - E_ORIG; }
  int pos = atomicAdd(&cursor[dst * NCHUNK + (src >> 12)], 1);
  csr_src[pos] = src;
}

// ============ bf16 MFMA GEMM: C[M,N] = A[M,K] @ Bt[N,K]^T ============
__global__ __launch_bounds__(256) void mfma_gemm_bf16(
    const ushort* __restrict__ A, const ushort* __restrict__ Bt,
    ushort* __restrict__ C, int M, int K, int N)
{
  __shared__ char smem[36864];
  ushort* As = (ushort*)smem;           // [128][64]
  ushort* Bs = As + 8192;               // [128][64]

  const int mtiles = (M + 127) >> 7;
  const int bid = blockIdx.x;
  const int xcd = bid & 7;
  const int i = bid >> 3;
  const int n0 = (i / 20) << 7;
  const int m = xcd + ((i % 20) << 3);
  if (m >= mtiles) return;
  const int m0 = m << 7;

  const int tid = threadIdx.x;
  const int lane = tid & 63;
  const int w = tid >> 6;
  const int wm = (w >> 1) << 6;
  const int wn = (w & 1) << 6;
  const int quad = lane >> 4;
  const int l15 = lane & 15;

  f32x4 acc[4][4] = {};

  for (int k0 = 0; k0 < K; k0 += 64) {
    #pragma unroll
    for (int r = 0; r < 4; r++) {
      int c = (r << 8) + tid;
      int row = c >> 3;
      int col = (c & 7) << 3;
      int ga = m0 + row; if (ga >= M) ga = M - 1;
      gl_lds16(A  + (size_t)ga * K + k0 + col, (char*)As + c * 16);
      gl_lds16(Bt + (size_t)(n0 + row) * K + k0 + col, (char*)Bs + c * 16);
    }
    __syncthreads();
    #pragma unroll
    for (int ks = 0; ks < 2; ks++) {
      bf16x8 af[4], bfr[4];
      #pragma unroll
      for (int ii = 0; ii < 4; ii++)
        af[ii]  = *(const bf16x8*)&As[(wm + (ii << 4) + l15) * 64 + (ks << 5) + (quad << 3)];
      #pragma unroll
      for (int j = 0; j < 4; j++)
        bfr[j] = *(const bf16x8*)&Bs[(wn + (j << 4) + l15) * 64 + (ks << 5) + (quad << 3)];
      #pragma unroll
      for (int ii = 0; ii < 4; ii++)
        #pragma unroll
        for (int j = 0; j < 4; j++)
          acc[ii][j] = __builtin_amdgcn_mfma_f32_16x16x32_bf16(
              af[ii], bfr[j], acc[ii][j], 0, 0, 0);
    }
    __syncthreads();
  }

  ushort* Cs = (ushort*)smem + w * 4608;
  #pragma unroll
  for (int ii = 0; ii < 4; ii++)
    #pragma unroll
    for (int j = 0; j < 4; j++)
      #pragma unroll
      for (int r = 0; r < 4; r++)
        Cs[((ii << 4) + (quad << 2) + r) * 72 + (j << 4) + l15] = f2bf(acc[ii][j][r]);
  #pragma unroll
  for (int it = 0; it < 8; it++) {
    int row = (it << 3) + (lane >> 3);
    int cc = lane & 7;
    bf16x8 v = *(const bf16x8*)&Cs[row * 72 + (cc << 3)];
    int grow = m0 + wm + row;
    if (grow < M)
      *(bf16x8*)&C[(size_t)grow * N + n0 + wn + (cc << 3)] = v;
  }
}

// ============ GATv2 edge phase, H=4, bf16, 4-wide unrolled ============
__device__ __forceinline__ void h4_term(
    float4 xlv, const float4& xrv, const float4& attv, float& v)
{
  float4 a;
  a.x = xlv.x + xrv.x; a.y = xlv.y + xrv.y;
  a.z = xlv.z + xrv.z; a.w = xlv.w + xrv.w;
  a.x = fmaxf(a.x, 0.2f * a.x); a.y = fmaxf(a.y, 0.2f * a.y);
  a.z = fmaxf(a.z, 0.2f * a.z); a.w = fmaxf(a.w, 0.2f * a.w);
  v = a.x * attv.x + a.y * attv.y + a.z * attv.z + a.w * attv.w;
}

__global__ __launch_bounds__(256) void gat_gather_h4(
    const ushort* __restrict__ Cin, const float* __restrict__ att,
    const float* __restrict__ bias, const int* __restrict__ rowptr,
    const int* __restrict__ csr_src, ushort* __restrict__ hout)
{
  const int n = blockIdx.x * 4 + (threadIdx.x >> 6);
  const int lane = threadIdx.x & 63;
  const int c4 = lane << 2;
  const float4 xrv  = ld_bf16x4(Cin + (size_t)n * 512 + 256 + c4);
  const float4 attv = *(const float4*)&att[c4];
  const int beg = rowptr[n * NCHUNK], end = rowptr[n * NCHUNK + NCHUNK];
  float4 acc = make_float4(0.f, 0.f, 0.f, 0.f);
  float lsum = 0.f;
  int p = beg;
  for (; p + 3 < end; p += 4) {
    int s0 = csr_src[p],     s1 = csr_src[p + 1];
    int s2 = csr_src[p + 2], s3 = csr_src[p + 3];
    float4 x0 = ld_bf16x4(Cin + (size_t)s0 * 512 + c4);
    float4 x1 = ld_bf16x4(Cin + (size_t)s1 * 512 + c4);
    float4 x2 = ld_bf16x4(Cin + (size_t)s2 * 512 + c4);
    float4 x3 = ld_bf16x4(Cin + (size_t)s3 * 512 + c4);
    float v0, v1, v2, v3;
    h4_term(x0, xrv, attv, v0); h4_term(x1, xrv, attv, v1);
    h4_term(x2, xrv, attv, v2); h4_term(x3, xrv, attv, v3);
    v0 += __shfl_xor(v0, 1); v1 += __shfl_xor(v1, 1);
    v2 += __shfl_xor(v2, 1); v3 += __shfl_xor(v3, 1);
    v0 += __shfl_xor(v0, 2); v1 += __shfl_xor(v1, 2);
    v2 += __shfl_xor(v2, 2); v3 += __shfl_xor(v3, 2);
    v0 += __shfl_xor(v0, 4); v1 += __shfl_xor(v1, 4);
    v2 += __shfl_xor(v2, 4); v3 += __shfl_xor(v3, 4);
    v0 += __shfl_xor(v0, 8); v1 += __shfl_xor(v1, 8);
    v2 += __shfl_xor(v2, 8); v3 += __shfl_xor(v3, 8);
    float w0 = __expf(v0), w1 = __expf(v1);
    float w2 = __expf(v2), w3 = __expf(v3);
    lsum += (w0 + w1) + (w2 + w3);
    acc.x += w0 * x0.x + w1 * x1.x + w2 * x2.x + w3 * x3.x;
    acc.y += w0 * x0.y + w1 * x1.y + w2 * x2.y + w3 * x3.y;
    acc.z += w0 * x0.z + w1 * x1.z + w2 * x2.z + w3 * x3.z;
    acc.w += w0 * x0.w + w1 * x1.w + w2 * x2.w + w3 * x3.w;
  }
  for (; p < end; p++) {
    int s0 = csr_src[p];
    float4 x0 = ld_bf16x4(Cin + (size_t)s0 * 512 + c4);
    float v0;
    h4_term(x0, xrv, attv, v0);
    v0 += __shfl_xor(v0, 1);
    v0 += __shfl_xor(v0, 2);
    v0 += __shfl_xor(v0, 4);
    v0 += __shfl_xor(v0, 8);
    float w0 = __expf(v0);
    lsum += w0;
    acc.x += w0 * x0.x; acc.y += w0 * x0.y; acc.z += w0 * x0.z; acc.w += w0 * x0.w;
  }
  const float4 bv = *(const float4*)&bias[c4];
  float inv = 1.f / lsum;
  ushort4 o;
  o.x = f2bf(acc.x * inv + bv.x); o.y = f2bf(acc.y * inv + bv.y);
  o.z = f2bf(acc.z * inv + bv.z); o.w = f2bf(acc.w * inv + bv.w);
  *(ushort4*)&hout[(size_t)n * 256 + c4] = o;
}

// ============ layer 2 (H=1): 4 edges/wave via 16-lane groups ============
__global__ __launch_bounds__(256) void gat_gather_h1(
    const ushort* __restrict__ Cin, const float* __restrict__ att,
    const float* __restrict__ bias, const int* __restrict__ rowptr,
    const int* __restrict__ csr_src, float* __restrict__ h3)
{
  const int n = blockIdx.x * 4 + (threadIdx.x >> 6);
  const int lane = threadIdx.x & 63;
  const int g = lane >> 4, c4 = (lane & 15) << 2;
  const float4 xrv  = ld_bf16x4(Cin + (size_t)n * 128 + 64 + c4);
  const float4 attv = *(const float4*)&att[c4];
  const int beg = rowptr[n * NCHUNK], end = rowptr[n * NCHUNK + NCHUNK];
  float4 acc = make_float4(0.f, 0.f, 0.f, 0.f);
  float lsum = 0.f;
  for (int p = beg + g; p < end; p += 4) {
    int src = csr_src[p];
    float4 xlv = ld_bf16x4(Cin + (size_t)src * 128 + c4);
    float v;
    h4_term(xlv, xrv, attv, v);
    v += __shfl_xor(v, 1);
    v += __shfl_xor(v, 2);
    v += __shfl_xor(v, 4);
    v += __shfl_xor(v, 8);
    float w = __expf(v);
    lsum += w;
    acc.x += w * xlv.x; acc.y += w * xlv.y;
    acc.z += w * xlv.z; acc.w += w * xlv.w;
  }
  #pragma unroll
  for (int off = 16; off <= 32; off <<= 1) {
    lsum  += __shfl_xor(lsum, off);
    acc.x += __shfl_xor(acc.x, off); acc.y += __shfl_xor(acc.y, off);
    acc.z += __shfl_xor(acc.z, off); acc.w += __shfl_xor(acc.w, off);
  }
  if (g == 0) {
    const float4 bv = *(const float4*)&bias[c4];
    float inv = 1.f / lsum;
    float4 o;
    o.x = acc.x * inv + bv.x; o.y = acc.y * inv + bv.y;
    o.z = acc.z * inv + bv.z; o.w = acc.w * inv + bv.w;
    *(float4*)&h3[(size_t)n * 64 + c4] = o;
  }
}

// ============ fused segmented pool (batch sorted) + BN + fc ============
__global__ __launch_bounds__(256) void pool_bn_fc(
    const float* __restrict__ h3, const int* __restrict__ batch,
    const float* __restrict__ gamma, const float* __restrict__ beta,
    const float* __restrict__ mean, const float* __restrict__ var,
    const float* __restrict__ fcw, const float* __restrict__ fcb,
    float* __restrict__ out)
{
  __shared__ float red[256];
  __shared__ float s[64];
  const int g = blockIdx.x;
  const int t = threadIdx.x;
  const int c = t & 63, r = t >> 6;
  int lo = 0, hi = N_NODES;
  while (lo < hi) { int mid = (lo + hi) >> 1; if (batch[mid] < g) lo = mid + 1; else hi = mid; }
  int s0 = lo;
  hi = N_NODES;
  while (lo < hi) { int mid = (lo + hi) >> 1; if (batch[mid] < g + 1) lo = mid + 1; else hi = mid; }
  int e0 = lo;
  float a = 0.f;
  for (int n = s0 + r; n < e0; n += 4) a += h3[(size_t)n * 64 + c];
  red[t] = a;
  __syncthreads();
  if (r == 0) {
    float p = red[c] + red[c + 64] + red[c + 128] + red[c + 192];
    s[c] = (p - mean[c]) * rsqrtf(var[c] + 1e-5f) * gamma[c] + beta[c];
  }
  __syncthreads();
  if (t < 32) {
    float acc = fcb[t];
    #pragma unroll
    for (int k = 0; k < 64; k++) acc += s[k] * fcw[k * 32 + t];
    out[g * 32 + t] = acc;
  }
}

extern "C" void kernel_launch(void* const* d_in, const int* in_sizes, int n_in,
                              void* d_out, int out_size, void* d_ws, size_t ws_size,
                              hipStream_t stream) {
  const float* x    = (const float*)d_in[0];
  const int*   ei   = (const int*)d_in[1];
  const int*   batch= (const int*)d_in[2];
  const float* Wl0  = (const float*)d_in[3];
  const float* Wr0  = (const float*)d_in[4];
  const float* att0 = (const float*)d_in[5];
  const float* b0   = (const float*)d_in[6];
  const float* Wl1  = (const float*)d_in[7];
  const float* Wr1  = (const float*)d_in[8];
  const float* att1 = (const float*)d_in[9];
  const float* b1   = (const float*)d_in[10];
  const float* Wl2  = (const float*)d_in[11];
  const float* Wr2  = (const float*)d_in[12];
  const float* att2 = (const float*)d_in[13];
  const float* b2   = (const float*)d_in[14];
  const float* bng  = (const float*)d_in[15];
  const float* bnb  = (const float*)d_in[16];
  const float* bnm  = (const float*)d_in[17];
  const float* bnv  = (const float*)d_in[18];
  const float* fcw  = (const float*)d_in[19];
  const float* fcb  = (const float*)d_in[20];
  float* out = (float*)d_out;

  const int* esrc = ei;
  const int* edst = ei + E_ORIG;

  // ---- workspace layout ----
  char* w = (char*)d_ws;
  ushort* x16  = (ushort*)w;                 w += (size_t)N_NODES * 128 * 2;
  ushort* Cbig = (ushort*)w;                 w += (size_t)N_NODES * 512 * 2;
  ushort* h16  = (ushort*)w;                 w += (size_t)N_NODES * 256 * 2;
  ushort* C2   = (ushort*)w;                 w += (size_t)N_NODES * 128 * 2;
  float*  h3   = (float*)w;                  w += (size_t)N_NODES * 64 * 4;
  ushort* Bt0  = (ushort*)w;                 w += (size_t)512 * 128 * 2;
  ushort* Bt1  = (ushort*)w;                 w += (size_t)512 * 256 * 2;
  ushort* Bt2  = (ushort*)w;                 w += (size_t)128 * 256 * 2;
  int* deg     = (int*)w;                    w += NBINS * 4;
  int* rowptr  = (int*)w;                    w += (NBINS + 1) * 4;
  int* cursor  = (int*)w;                    w += NBINS * 4;
  int* bsum    = (int*)w;                    w += 128 * 4;
  int* boff    = (int*)w;                    w += 128 * 4;
  int* csr_src = (int*)w;

  dim3 blk(256);
  const int eblk = (E_TOT + 255) / 256;

  // ---- prep: cast + pack all weights + zero bins (one launch) ----
  prep<<<dim3(3495), blk, 0, stream>>>(
      x, Wl0, Wr0, Wl1, Wr1, Wl2, Wr2, x16, Bt0, Bt1, Bt2, deg);

  // ---- CSR build, (dst, src-chunk) binned; 3-phase parallel scan ----
  deg_count<<<dim3(eblk), blk, 0, stream>>>(esrc, edst, deg);
  scan1<<<dim3(SCAN_BLOCKS), blk, 0, stream>>>(deg, bsum);
  scan2<<<dim3(1), dim3(128), 0, stream>>>(bsum, boff, rowptr);
  scan3<<<dim3(SCAN_BLOCKS), blk, 0, stream>>>(deg, boff, rowptr, cursor);
  csr_fill<<<dim3(eblk), blk, 0, stream>>>(esrc, edst, cursor, csr_src);

  // ---- layer 0 ----
  mfma_gemm_bf16<<<dim3(160 * 4), blk, 0, stream>>>(x16, Bt0, Cbig, N_NODES, 128, 512);
  gat_gather_h4<<<dim3(N_NODES / 4), blk, 0, stream>>>(
      Cbig, att0, b0, rowptr, csr_src, h16);

  // ---- layer 1 ----
  mfma_gemm_bf16<<<dim3(160 * 4), blk, 0, stream>>>(h16, Bt1, Cbig, N_NODES, 256, 512);
  gat_gather_h4<<<dim3(N_NODES / 4), blk, 0, stream>>>(
      Cbig, att1, b1, rowptr, csr_src, h16);

  // ---- layer 2 ----
  mfma_gemm_bf16<<<dim3(160 * 1), blk, 0, stream>>>(h16, Bt2, C2, N_NODES, 256, 128);
  gat_gather_h1<<<dim3(N_NODES / 4), blk, 0, stream>>>(
      C2, att2, b2, rowptr, csr_src, h3);

  // ---- pool + BN + fc ----
  pool_bn_fc<<<dim3(NUM_GRAPHS), blk, 0, stream>>>(
      h3, batch, bng, bnb, bnm, bnv, fcw, fcb, out);
}

// Round 9
// 286.302 us; speedup vs baseline: 1.8616x; 1.0116x over previous
//
#include <hip/hip_runtime.h>
#include <math.h>

#define N_NODES 20000
#define E_ORIG  320000
#define E_TOT   340000
#define NUM_GRAPHS 64
#define NCHUNK 5            // src chunks of 4096 rows -> (dst,chunk) binned CSR
#define NBINS (N_NODES * NCHUNK)
#define SCAN_BLOCKS 98      // 98 * 1024 = 100352 >= NBINS

typedef __attribute__((ext_vector_type(8))) short bf16x8;
typedef __attribute__((ext_vector_type(4))) float f32x4;

// fp32 -> bf16 RNE
__device__ __forceinline__ ushort f2bf(float x) {
  unsigned u = __float_as_uint(x);
  return (ushort)((u + 0x7fffu + ((u >> 16) & 1u)) >> 16);
}
// 4 consecutive bf16 -> float4 (8B load)
__device__ __forceinline__ float4 ld_bf16x4(const ushort* p) {
  ushort4 u = *(const ushort4*)p;
  float4 f;
  f.x = __uint_as_float((unsigned)u.x << 16);
  f.y = __uint_as_float((unsigned)u.y << 16);
  f.z = __uint_as_float((unsigned)u.z << 16);
  f.w = __uint_as_float((unsigned)u.w << 16);
  return f;
}
// async global->LDS, 16B per lane; lds dest is wave-uniform base + lane*16
__device__ __forceinline__ void gl_lds16(const void* g, void* l) {
  __builtin_amdgcn_global_load_lds(
      (const __attribute__((address_space(1))) unsigned*)(uintptr_t)g,
      (__attribute__((address_space(3))) unsigned*)(uintptr_t)l, 16, 0, 0);
}

// ============ merged prep: cast x, pack weights, zero (dst,chunk) bins ======
__global__ __launch_bounds__(256) void prep(
    const float* __restrict__ x,
    const float* __restrict__ Wl0, const float* __restrict__ Wr0,
    const float* __restrict__ Wl1, const float* __restrict__ Wr1,
    const float* __restrict__ Wl2, const float* __restrict__ Wr2,
    ushort* __restrict__ x16, ushort* __restrict__ Bt0,
    ushort* __restrict__ Bt1, ushort* __restrict__ Bt2, int* __restrict__ deg)
{
  const int Z0 = 640000;           // x cast, float4 granules (20000*128/4)
  const int Z1 = Z0 + 65536;       // Bt0: 512(n) x 128(k)
  const int Z2 = Z1 + 131072;      // Bt1: 512 x 256
  const int Z3 = Z2 + 32768;       // Bt2: 128 x 256
  const int Z4 = Z3 + NBINS / 4;   // deg zero, int4 granules (100000 ints)
  int t = blockIdx.x * 256 + threadIdx.x;
  if (t < Z0) {
    int i = t << 2;
    float4 v = *(const float4*)&x[i];
    ushort4 o; o.x = f2bf(v.x); o.y = f2bf(v.y); o.z = f2bf(v.z); o.w = f2bf(v.w);
    *(ushort4*)&x16[i] = o;
  } else if (t < Z1) {
    int idx = t - Z0; int n = idx >> 7, k = idx & 127;
    float v = (n < 256) ? Wl0[k * 256 + n] : Wr0[k * 256 + (n - 256)];
    Bt0[idx] = f2bf(v);
  } else if (t < Z2) {
    int idx = t - Z1; int n = idx >> 8, k = idx & 255;
    float v = (n < 256) ? Wl1[k * 256 + n] : Wr1[k * 256 + (n - 256)];
    Bt1[idx] = f2bf(v);
  } else if (t < Z3) {
    int idx = t - Z2; int n = idx >> 8, k = idx & 255;
    float v = (n < 64) ? Wl2[k * 64 + n] : Wr2[k * 64 + (n - 64)];
    Bt2[idx] = f2bf(v);
  } else if (t < Z4) {
    int4 z = {0, 0, 0, 0};
    *(int4*)&deg[(t - Z3) << 2] = z;
  }
}

// ============ CSR build, binned by (dst, src-chunk) ============

__global__ __launch_bounds__(256) void deg_count(
    const int* __restrict__ esrc, const int* __restrict__ edst,
    int* __restrict__ deg)
{
  int e = blockIdx.x * 256 + threadIdx.x;
  if (e >= E_TOT) return;
  int src, dst;
  if (e < E_ORIG) { src = esrc[e]; dst = edst[e]; }
  else            { src = dst = e - E_ORIG; }
  atomicAdd(&deg[dst * NCHUNK + (src >> 12)], 1);
}

// phase 1: per-block (1024 ints) reduction -> bsum[SCAN_BLOCKS]
__global__ __launch_bounds__(256) void scan1(
    const int* __restrict__ deg, int* __restrict__ bsum)
{
  __shared__ int red[256];
  const int t = threadIdx.x;
  int base = (blockIdx.x << 10) + (t << 2);
  int s = 0;
  if (base + 4 <= NBINS) {
    int4 v = *(const int4*)&deg[base];
    s = v.x + v.y + v.z + v.w;
  }
  red[t] = s;
  __syncthreads();
  #pragma unroll
  for (int off = 128; off > 0; off >>= 1) {
    if (t < off) red[t] += red[t + off];
    __syncthreads();
  }
  if (t == 0) bsum[blockIdx.x] = red[0];
}

// phase 2 (merged): each block scans the 98 partials in LDS, then local scan
__global__ __launch_bounds__(256) void scan3(
    const int* __restrict__ deg, const int* __restrict__ bsum,
    int* __restrict__ rowptr, int* __restrict__ cursor)
{
  __shared__ int sc[256];
  __shared__ int bs[128];
  const int t = threadIdx.x;
  if (t < 128) bs[t] = (t < SCAN_BLOCKS) ? bsum[t] : 0;
  __syncthreads();
  #pragma unroll
  for (int off = 1; off < 128; off <<= 1) {
    int v = (t >= off && t < 128) ? bs[t - off] : 0;
    __syncthreads();
    if (t < 128) bs[t] += v;
    __syncthreads();
  }
  const int myoff = (blockIdx.x == 0) ? 0 : bs[blockIdx.x - 1];

  int base = (blockIdx.x << 10) + (t << 2);
  int4 v = {0, 0, 0, 0};
  if (base + 4 <= NBINS) v = *(const int4*)&deg[base];
  int s = v.x + v.y + v.z + v.w;
  sc[t] = s;
  __syncthreads();
  #pragma unroll
  for (int off = 1; off < 256; off <<= 1) {
    int u = (t >= off) ? sc[t - off] : 0;
    __syncthreads();
    sc[t] += u;
    __syncthreads();
  }
  if (base + 4 <= NBINS) {
    int p = myoff + ((t == 0) ? 0 : sc[t - 1]);
    int4 r;
    r.x = p; r.y = p + v.x; r.z = r.y + v.y; r.w = r.z + v.z;
    *(int4*)&rowptr[base] = r;
    *(int4*)&cursor[base] = r;
  }
  if (blockIdx.x == SCAN_BLOCKS - 1 && t == 255) rowptr[NBINS] = bs[127];
}

__global__ __launch_bounds__(256) void csr_fill(
    const int* __restrict__ esrc, const int* __restrict__ edst,
    int* __restrict__ cursor, int* __restrict__ csr_src)
{
  int e = blockIdx.x * 256 + threadIdx.x;
  if (e >= E_TOT) return;
  int src, dst;
  if (e < E_ORIG) { src = esrc[e]; dst = edst[e]; }
  else            { src = dst = e - E_ORIG; }
  int pos = atomicAdd(&cursor[dst * NCHUNK + (src >> 12)], 1);
  csr_src[pos] = src;
}

// ============ bf16 MFMA GEMM: C[M,N] = A[M,K] @ Bt[N,K]^T ============
__global__ __launch_bounds__(256) void mfma_gemm_bf16(
    const ushort* __restrict__ A, const ushort* __restrict__ Bt,
    ushort* __restrict__ C, int M, int K, int N)
{
  __shared__ char smem[36864];
  ushort* As = (ushort*)smem;           // [128][64]
  ushort* Bs = As + 8192;               // [128][64]

  const int mtiles = (M + 127) >> 7;
  const int bid = blockIdx.x;
  const int xcd = bid & 7;
  const int i = bid >> 3;
  const int n0 = (i / 20) << 7;
  const int m = xcd + ((i % 20) << 3);
  if (m >= mtiles) return;
  const int m0 = m << 7;

  const int tid = threadIdx.x;
  const int lane = tid & 63;
  const int w = tid >> 6;
  const int wm = (w >> 1) << 6;
  const int wn = (w & 1) << 6;
  const int quad = lane >> 4;
  const int l15 = lane & 15;

  f32x4 acc[4][4] = {};

  for (int k0 = 0; k0 < K; k0 += 64) {
    #pragma unroll
    for (int r = 0; r < 4; r++) {
      int c = (r << 8) + tid;
      int row = c >> 3;
      int col = (c & 7) << 3;
      int ga = m0 + row; if (ga >= M) ga = M - 1;
      gl_lds16(A  + (size_t)ga * K + k0 + col, (char*)As + c * 16);
      gl_lds16(Bt + (size_t)(n0 + row) * K + k0 + col, (char*)Bs + c * 16);
    }
    __syncthreads();
    #pragma unroll
    for (int ks = 0; ks < 2; ks++) {
      bf16x8 af[4], bfr[4];
      #pragma unroll
      for (int ii = 0; ii < 4; ii++)
        af[ii]  = *(const bf16x8*)&As[(wm + (ii << 4) + l15) * 64 + (ks << 5) + (quad << 3)];
      #pragma unroll
      for (int j = 0; j < 4; j++)
        bfr[j] = *(const bf16x8*)&Bs[(wn + (j << 4) + l15) * 64 + (ks << 5) + (quad << 3)];
      #pragma unroll
      for (int ii = 0; ii < 4; ii++)
        #pragma unroll
        for (int j = 0; j < 4; j++)
          acc[ii][j] = __builtin_amdgcn_mfma_f32_16x16x32_bf16(
              af[ii], bfr[j], acc[ii][j], 0, 0, 0);
    }
    __syncthreads();
  }

  ushort* Cs = (ushort*)smem + w * 4608;
  #pragma unroll
  for (int ii = 0; ii < 4; ii++)
    #pragma unroll
    for (int j = 0; j < 4; j++)
      #pragma unroll
      for (int r = 0; r < 4; r++)
        Cs[((ii << 4) + (quad << 2) + r) * 72 + (j << 4) + l15] = f2bf(acc[ii][j][r]);
  #pragma unroll
  for (int it = 0; it < 8; it++) {
    int row = (it << 3) + (lane >> 3);
    int cc = lane & 7;
    bf16x8 v = *(const bf16x8*)&Cs[row * 72 + (cc << 3)];
    int grow = m0 + wm + row;
    if (grow < M)
      *(bf16x8*)&C[(size_t)grow * N + n0 + wn + (cc << 3)] = v;
  }
}

// ============ GATv2 edge phase, H=4, bf16, 8 edges in flight ============
__device__ __forceinline__ void h4_term(
    float4 xlv, const float4& xrv, const float4& attv, float& v)
{
  float4 a;
  a.x = xlv.x + xrv.x; a.y = xlv.y + xrv.y;
  a.z = xlv.z + xrv.z; a.w = xlv.w + xrv.w;
  a.x = fmaxf(a.x, 0.2f * a.x); a.y = fmaxf(a.y, 0.2f * a.y);
  a.z = fmaxf(a.z, 0.2f * a.z); a.w = fmaxf(a.w, 0.2f * a.w);
  v = a.x * attv.x + a.y * attv.y + a.z * attv.z + a.w * attv.w;
}

// per-head 16-lane butterfly + exp + accumulate for one edge
__device__ __forceinline__ void h4_edge(
    const float4& xv, const float4& xrv, const float4& attv,
    float4& acc, float& lsum)
{
  float v;
  h4_term(xv, xrv, attv, v);
  v += __shfl_xor(v, 1);
  v += __shfl_xor(v, 2);
  v += __shfl_xor(v, 4);
  v += __shfl_xor(v, 8);
  float w = __expf(v);            // no-max softmax: logits O(1), safe
  lsum += w;
  acc.x += w * xv.x; acc.y += w * xv.y;
  acc.z += w * xv.z; acc.w += w * xv.w;
}

__global__ __launch_bounds__(256) void gat_gather_h4(
    const ushort* __restrict__ Cin, const float* __restrict__ att,
    const float* __restrict__ bias, const int* __restrict__ rowptr,
    const int* __restrict__ csr_src, ushort* __restrict__ hout)
{
  const int n = blockIdx.x * 4 + (threadIdx.x >> 6);
  const int lane = threadIdx.x & 63;
  const int c4 = lane << 2;
  const float4 xrv  = ld_bf16x4(Cin + (size_t)n * 512 + 256 + c4);
  const float4 attv = *(const float4*)&att[c4];
  const int beg = rowptr[n * NCHUNK], end = rowptr[n * NCHUNK + NCHUNK];
  float4 acc = make_float4(0.f, 0.f, 0.f, 0.f);
  float lsum = 0.f;
  int p = beg;
  for (; p + 7 < end; p += 8) {        // 8 loads issued before any consume
    int s0 = csr_src[p],     s1 = csr_src[p + 1];
    int s2 = csr_src[p + 2], s3 = csr_src[p + 3];
    int s4 = csr_src[p + 4], s5 = csr_src[p + 5];
    int s6 = csr_src[p + 6], s7 = csr_src[p + 7];
    float4 x0 = ld_bf16x4(Cin + (size_t)s0 * 512 + c4);
    float4 x1 = ld_bf16x4(Cin + (size_t)s1 * 512 + c4);
    float4 x2 = ld_bf16x4(Cin + (size_t)s2 * 512 + c4);
    float4 x3 = ld_bf16x4(Cin + (size_t)s3 * 512 + c4);
    float4 x4 = ld_bf16x4(Cin + (size_t)s4 * 512 + c4);
    float4 x5 = ld_bf16x4(Cin + (size_t)s5 * 512 + c4);
    float4 x6 = ld_bf16x4(Cin + (size_t)s6 * 512 + c4);
    float4 x7 = ld_bf16x4(Cin + (size_t)s7 * 512 + c4);
    h4_edge(x0, xrv, attv, acc, lsum);
    h4_edge(x1, xrv, attv, acc, lsum);
    h4_edge(x2, xrv, attv, acc, lsum);
    h4_edge(x3, xrv, attv, acc, lsum);
    h4_edge(x4, xrv, attv, acc, lsum);
    h4_edge(x5, xrv, attv, acc, lsum);
    h4_edge(x6, xrv, attv, acc, lsum);
    h4_edge(x7, xrv, attv, acc, lsum);
  }
  for (; p + 3 < end; p += 4) {
    int s0 = csr_src[p],     s1 = csr_src[p + 1];
    int s2 = csr_src[p + 2], s3 = csr_src[p + 3];
    float4 x0 = ld_bf16x4(Cin + (size_t)s0 * 512 + c4);
    float4 x1 = ld_bf16x4(Cin + (size_t)s1 * 512 + c4);
    float4 x2 = ld_bf16x4(Cin + (size_t)s2 * 512 + c4);
    float4 x3 = ld_bf16x4(Cin + (size_t)s3 * 512 + c4);
    h4_edge(x0, xrv, attv, acc, lsum);
    h4_edge(x1, xrv, attv, acc, lsum);
    h4_edge(x2, xrv, attv, acc, lsum);
    h4_edge(x3, xrv, attv, acc, lsum);
  }
  for (; p < end; p++) {
    int s0 = csr_src[p];
    float4 x0 = ld_bf16x4(Cin + (size_t)s0 * 512 + c4);
    h4_edge(x0, xrv, attv, acc, lsum);
  }
  const float4 bv = *(const float4*)&bias[c4];
  float inv = 1.f / lsum;
  ushort4 o;
  o.x = f2bf(acc.x * inv + bv.x); o.y = f2bf(acc.y * inv + bv.y);
  o.z = f2bf(acc.z * inv + bv.z); o.w = f2bf(acc.w * inv + bv.w);
  *(ushort4*)&hout[(size_t)n * 256 + c4] = o;
}

// ============ layer 2 (H=1): 16-lane groups, 2 edges in flight ============
__global__ __launch_bounds__(256) void gat_gather_h1(
    const ushort* __restrict__ Cin, const float* __restrict__ att,
    const float* __restrict__ bias, const int* __restrict__ rowptr,
    const int* __restrict__ csr_src, float* __restrict__ h3)
{
  const int n = blockIdx.x * 4 + (threadIdx.x >> 6);
  const int lane = threadIdx.x & 63;
  const int g = lane >> 4, c4 = (lane & 15) << 2;
  const float4 xrv  = ld_bf16x4(Cin + (size_t)n * 128 + 64 + c4);
  const float4 attv = *(const float4*)&att[c4];
  const int beg = rowptr[n * NCHUNK], end = rowptr[n * NCHUNK + NCHUNK];
  float4 acc = make_float4(0.f, 0.f, 0.f, 0.f);
  float lsum = 0.f;
  int p = beg + g;
  for (; p + 4 < end; p += 8) {        // 2 strided edges in flight
    int s0 = csr_src[p], s1 = csr_src[p + 4];
    float4 x0 = ld_bf16x4(Cin + (size_t)s0 * 128 + c4);
    float4 x1 = ld_bf16x4(Cin + (size_t)s1 * 128 + c4);
    h4_edge(x0, xrv, attv, acc, lsum);
    h4_edge(x1, xrv, attv, acc, lsum);
  }
  if (p < end) {
    int s0 = csr_src[p];
    float4 x0 = ld_bf16x4(Cin + (size_t)s0 * 128 + c4);
    h4_edge(x0, xrv, attv, acc, lsum);
  }
  #pragma unroll
  for (int off = 16; off <= 32; off <<= 1) {
    lsum  += __shfl_xor(lsum, off);
    acc.x += __shfl_xor(acc.x, off); acc.y += __shfl_xor(acc.y, off);
    acc.z += __shfl_xor(acc.z, off); acc.w += __shfl_xor(acc.w, off);
  }
  if (g == 0) {
    const float4 bv = *(const float4*)&bias[c4];
    float inv = 1.f / lsum;
    float4 o;
    o.x = acc.x * inv + bv.x; o.y = acc.y * inv + bv.y;
    o.z = acc.z * inv + bv.z; o.w = acc.w * inv + bv.w;
    *(float4*)&h3[(size_t)n * 64 + c4] = o;
  }
}

// ============ fused segmented pool (batch sorted) + BN + fc ============
__global__ __launch_bounds__(256) void pool_bn_fc(
    const float* __restrict__ h3, const int* __restrict__ batch,
    const float* __restrict__ gamma, const float* __restrict__ beta,
    const float* __restrict__ mean, const float* __restrict__ var,
    const float* __restrict__ fcw, const float* __restrict__ fcb,
    float* __restrict__ out)
{
  __shared__ float red[256];
  __shared__ float s[64];
  const int g = blockIdx.x;
  const int t = threadIdx.x;
  const int c = t & 63, r = t >> 6;
  int lo = 0, hi = N_NODES;
  while (lo < hi) { int mid = (lo + hi) >> 1; if (batch[mid] < g) lo = mid + 1; else hi = mid; }
  int s0 = lo;
  hi = N_NODES;
  while (lo < hi) { int mid = (lo + hi) >> 1; if (batch[mid] < g + 1) lo = mid + 1; else hi = mid; }
  int e0 = lo;
  float a = 0.f;
  for (int n = s0 + r; n < e0; n += 4) a += h3[(size_t)n * 64 + c];
  red[t] = a;
  __syncthreads();
  if (r == 0) {
    float p = red[c] + red[c + 64] + red[c + 128] + red[c + 192];
    s[c] = (p - mean[c]) * rsqrtf(var[c] + 1e-5f) * gamma[c] + beta[c];
  }
  __syncthreads();
  if (t < 32) {
    float acc = fcb[t];
    #pragma unroll
    for (int k = 0; k < 64; k++) acc += s[k] * fcw[k * 32 + t];
    out[g * 32 + t] = acc;
  }
}

extern "C" void kernel_launch(void* const* d_in, const int* in_sizes, int n_in,
                              void* d_out, int out_size, void* d_ws, size_t ws_size,
                              hipStream_t stream) {
  const float* x    = (const float*)d_in[0];
  const int*   ei   = (const int*)d_in[1];
  const int*   batch= (const int*)d_in[2];
  const float* Wl0  = (const float*)d_in[3];
  const float* Wr0  = (const float*)d_in[4];
  const float* att0 = (const float*)d_in[5];
  const float* b0   = (const float*)d_in[6];
  const float* Wl1  = (const float*)d_in[7];
  const float* Wr1  = (const float*)d_in[8];
  const float* att1 = (const float*)d_in[9];
  const float* b1   = (const float*)d_in[10];
  const float* Wl2  = (const float*)d_in[11];
  const float* Wr2  = (const float*)d_in[12];
  const float* att2 = (const float*)d_in[13];
  const float* b2   = (const float*)d_in[14];
  const float* bng  = (const float*)d_in[15];
  const float* bnb  = (const float*)d_in[16];
  const float* bnm  = (const float*)d_in[17];
  const float* bnv  = (const float*)d_in[18];
  const float* fcw  = (const float*)d_in[19];
  const float* fcb  = (const float*)d_in[20];
  float* out = (float*)d_out;

  const int* esrc = ei;
  const int* edst = ei + E_ORIG;

  // ---- workspace layout ----
  char* w = (char*)d_ws;
  ushort* x16  = (ushort*)w;                 w += (size_t)N_NODES * 128 * 2;
  ushort* Cbig = (ushort*)w;                 w += (size_t)N_NODES * 512 * 2;
  ushort* h16  = (ushort*)w;                 w += (size_t)N_NODES * 256 * 2;
  ushort* C2   = (ushort*)w;                 w += (size_t)N_NODES * 128 * 2;
  float*  h3   = (float*)w;                  w += (size_t)N_NODES * 64 * 4;
  ushort* Bt0  = (ushort*)w;                 w += (size_t)512 * 128 * 2;
  ushort* Bt1  = (ushort*)w;                 w += (size_t)512 * 256 * 2;
  ushort* Bt2  = (ushort*)w;                 w += (size_t)128 * 256 * 2;
  int* deg     = (int*)w;                    w += NBINS * 4;
  int* rowptr  = (int*)w;                    w += (NBINS + 1) * 4;
  int* cursor  = (int*)w;                    w += NBINS * 4;
  int* bsum    = (int*)w;                    w += 128 * 4;
  int* csr_src = (int*)w;

  dim3 blk(256);
  const int eblk = (E_TOT + 255) / 256;

  // ---- prep: cast + pack all weights + zero bins (one launch) ----
  prep<<<dim3(3495), blk, 0, stream>>>(
      x, Wl0, Wr0, Wl1, Wr1, Wl2, Wr2, x16, Bt0, Bt1, Bt2, deg);

  // ---- CSR build, (dst, src-chunk) binned; 2-kernel parallel scan ----
  deg_count<<<dim3(eblk), blk, 0, stream>>>(esrc, edst, deg);
  scan1<<<dim3(SCAN_BLOCKS), blk, 0, stream>>>(deg, bsum);
  scan3<<<dim3(SCAN_BLOCKS), blk, 0, stream>>>(deg, bsum, rowptr, cursor);
  csr_fill<<<dim3(eblk), blk, 0, stream>>>(esrc, edst, cursor, csr_src);

  // ---- layer 0 ----
  mfma_gemm_bf16<<<dim3(160 * 4), blk, 0, stream>>>(x16, Bt0, Cbig, N_NODES, 128, 512);
  gat_gather_h4<<<dim3(N_NODES / 4), blk, 0, stream>>>(
      Cbig, att0, b0, rowptr, csr_src, h16);

  // ---- layer 1 ----
  mfma_gemm_bf16<<<dim3(160 * 4), blk, 0, stream>>>(h16, Bt1, Cbig, N_NODES, 256, 512);
  gat_gather_h4<<<dim3(N_NODES / 4), blk, 0, stream>>>(
      Cbig, att1, b1, rowptr, csr_src, h16);

  // ---- layer 2 ----
  mfma_gemm_bf16<<<dim3(160 * 1), blk, 0, stream>>>(h16, Bt2, C2, N_NODES, 256, 128);
  gat_gather_h1<<<dim3(N_NODES / 4), blk, 0, stream>>>(
      C2, att2, b2, rowptr, csr_src, h3);

  // ---- pool + BN + fc ----
  pool_bn_fc<<<dim3(NUM_GRAPHS), blk, 0, stream>>>(
      h3, batch, bng, bnb, bnm, bnv, fcw, fcb, out);
}